// Round 6
// baseline (151.051 us; speedup 1.0000x reference)
//
#include <hip/hip_runtime.h>
#include <hip/hip_bf16.h>
#include <cmath>

#define RAYS_PER_BLOCK 2
#define KS 84   // row stride in ushorts for A-buffer / W2T / aext (bank-decorrelated, 8B-aligned)

typedef __attribute__((ext_vector_type(4))) short  short4v;
typedef __attribute__((ext_vector_type(8))) short  short8v;
typedef __attribute__((ext_vector_type(16))) float f32x16;

__device__ __forceinline__ float sigm(float x){ return 1.0f/(1.0f + expf(-x)); }
__device__ __forceinline__ float clampf(float x, float lo, float hi){ return fminf(fmaxf(x, lo), hi); }
__device__ __forceinline__ unsigned short f2bf(float x){
  __hip_bfloat16 h = __float2bfloat16(x);
  return *reinterpret_cast<unsigned short*>(&h);
}
__device__ __forceinline__ unsigned pk2(float a, float b){
  return (unsigned)f2bf(a) | ((unsigned)f2bf(b) << 16);
}
__device__ __forceinline__ short8v lds_load8(const unsigned short* p){
  short4v lo = *(const short4v*)p;
  short4v hi = *(const short4v*)(p + 4);
  short8v r;
  r[0]=lo[0]; r[1]=lo[1]; r[2]=lo[2]; r[3]=lo[3];
  r[4]=hi[0]; r[5]=hi[1]; r[6]=hi[2]; r[7]=hi[3];
  return r;
}

// Single-launch fused kernel. Block = 2 rays x 128 threads.
// Phase 0 (per block): build A[c][k] (k<64: M=W2[:,1:]*Wc1[9:73,:] via MFMA;
// k=64..72: Wc1 rows 0..8; k=73: cb; k>=74: 0) in LDS, then each wave loads its
// af[10] A-fragments. A-buffer & W2T staging alias the s_aext region (dead until
// the fine pass; >=3 barriers in between).
__global__ __launch_bounds__(256)
void neus_render(const float* __restrict__ rays_o, const float* __restrict__ rays_d,
                 const float* __restrict__ W1, const float* __restrict__ b1,
                 const float* __restrict__ W2, const float* __restrict__ b2,
                 const float* __restrict__ Wc1, const float* __restrict__ bc1,
                 const float* __restrict__ Wc2, const float* __restrict__ bc2,
                 const float* __restrict__ inv_s_p, float* __restrict__ out)
{
  __shared__ unsigned short SU[4*64*KS];  // phase0: [ABUF | W2T | unused]; fine: per-wave aext
  __shared__ float4 s_w1[64];             // {W1[0][j],W1[1][j],W1[2][j],b1[j]}
  __shared__ float4 s_w1e[64];            // {eps*W1x, eps*W1y, eps*W1z, W2[j][0]}
  __shared__ float4 s_wc2[64];
  __shared__ float  s_z[RAYS_PER_BLOCK][64];
  __shared__ float  s_cdf[RAYS_PER_BLOCK][64];
  __shared__ float  s_newz[RAYS_PER_BLOCK][64];
  __shared__ float  s_zall[RAYS_PER_BLOCK][128];
  __shared__ float  s_red[RAYS_PER_BLOCK][2][4];
  __shared__ float  s_wtot[RAYS_PER_BLOCK][2];

  unsigned short* ABUF = SU;              // 64 x KS  (A[c][k] bf16)
  unsigned short* W2T  = SU + 64*KS;      // 64 x KS  (W2T[k][t] bf16)

  const int tid  = threadIdx.x;
  const int rs   = tid >> 7;
  const int lt   = tid & 127;
  const int lane = tid & 63;
  const int wir  = (tid >> 6) & 1;
  const int wv   = tid >> 6;
  const int l31  = lane & 31;
  const int h    = lane >> 5;
  const int ray  = blockIdx.x * RAYS_PER_BLOCK + rs;

  const float b20 = b2[0];

  // ================= PHASE 0: weight prep in-block =================
  // stage W2[:,1:65] -> W2T[k][t] bf16 (coalesced global reads)
  for (int i = tid; i < 4096; i += 256){
    int k = i >> 6, t = i & 63;
    W2T[k*KS + t] = f2bf(W2[k*65 + 1 + t]);
  }
  // W1 / W1E / Wc2 packs
  if (tid < 64){
    int j = tid;
    s_w1[j]  = make_float4(W1[j], W1[64+j], W1[128+j], b1[j]);
    s_w1e[j] = make_float4(0.005f*W1[j], 0.005f*W1[64+j], 0.005f*W1[128+j], W2[j*65]);
    s_wc2[j] = make_float4(Wc2[j*3], Wc2[j*3+1], Wc2[j*3+2], 0.f);
  }
  // ext rows k=64..72: Wc1 rows 0..8
  for (int i = tid; i < 576; i += 256){
    int ii = i >> 6, c = i & 63;
    ABUF[c*KS + 64 + ii] = f2bf(Wc1[ii*64 + c]);
  }
  // zeros k=74..79
  for (int i = tid; i < 384; i += 256){
    int z = i >> 6, c = i & 63;
    ABUF[c*KS + 74 + z] = 0;
  }
  // cb row (k=73): wave 3, lane = c
  if (wv == 3){
    float acc = bc1[lane];
    #pragma unroll 4
    for (int t = 0; t < 64; ++t) acc = fmaf(b2[1+t], Wc1[(9+t)*64 + lane], acc);
    ABUF[lane*KS + 73] = f2bf(acc);
  }
  __syncthreads();

  // per-wave MFMA tile of E[c][k] = sum_t Wc1[9+t][c] * W2[k][1+t]
  {
    const int mb = wv & 1, kb = wv >> 1;
    f32x16 e;
    #pragma unroll
    for (int i = 0; i < 16; ++i) e[i] = 0.f;
    #pragma unroll
    for (int s = 0; s < 4; ++s){
      short8v afr;
      #pragma unroll
      for (int j = 0; j < 8; ++j)
        afr[j] = (short)f2bf(Wc1[(9 + 16*s + 8*h + j)*64 + 32*mb + l31]);
      short8v bfr = lds_load8(&W2T[(32*kb + l31)*KS + 16*s + 8*h]);
      e = __builtin_amdgcn_mfma_f32_32x32x16_bf16(afr, bfr, e, 0, 0, 0);
    }
    const int kcol = 32*kb + l31;
    #pragma unroll
    for (int r = 0; r < 16; ++r){
      int c = 32*mb + (r & 3) + 8*(r >> 2) + 4*h;
      ABUF[c*KS + kcol] = f2bf(e[r]);
    }
  }
  __syncthreads();

  // each wave loads its A-fragments: af[mb*5+kk] = A[c=32mb+l31][16kk+8h+j]
  short8v af[10];
  #pragma unroll
  for (int f = 0; f < 10; ++f){
    int mb = f / 5, kk = f - 5*mb;
    af[f] = lds_load8(&ABUF[(32*mb + l31)*KS + 16*kk + 8*h]);
  }

  // ================= render (as before) =================
  float ox = rays_o[ray*3], oy = rays_o[ray*3+1], oz = rays_o[ray*3+2];
  float dx = rays_d[ray*3], dy = rays_d[ray*3+1], dz = rays_d[ray*3+2];
  float tnx = (-1.f-ox)/(dx+1e-15f), tfx = (1.f-ox)/(dx+1e-15f);
  float tny = (-1.f-oy)/(dy+1e-15f), tfy = (1.f-oy)/(dy+1e-15f);
  float tnz = (-1.f-oz)/(dz+1e-15f), tfz = (1.f-oz)/(dz+1e-15f);
  float nearv = fmaxf(fmaxf(fminf(tnx,tfx), fminf(tny,tfy)), fminf(tnz,tfz));
  float farv  = fminf(fminf(fmaxf(tnx,tfx), fmaxf(tny,tfy)), fmaxf(tnz,tfz));
  nearv = fmaxf(nearv, 0.05f);
  const float sd = (farv - nearv) * (1.f/64.f);

  // ---- coarse pass: wave 0 of each ray (lane = coarse sample) ----
  if (wir == 0){
    float zt = nearv + (farv-nearv) * ((float)lane * (1.f/63.f));
    float px = clampf(ox + dx*zt, -1.f, 1.f);
    float py = clampf(oy + dy*zt, -1.f, 1.f);
    float pz = clampf(oz + dz*zt, -1.f, 1.f);
    float acc = b20;
    #pragma unroll 8
    for (int j = 0; j < 64; ++j){
      float4 w = s_w1[j];
      acc += fmaxf(px*w.x + py*w.y + pz*w.z + w.w, 0.f) * s_w1e[j].w;
    }
    s_z[rs][lane] = zt;
    float s1  = __shfl_down(acc, 1);
    float zt1 = nearv + (farv-nearv) * ((float)(lane+1) * (1.f/63.f));
    float a_c = 0.f, qv = 1.f;
    if (lane < 63){
      float dc   = zt1 - zt;
      float mid  = 0.5f*(acc + s1);
      float cosv = clampf((s1-acc)/(dc+1e-5f), -1000.f, 0.f);
      float est  = cosv*dc*0.5f;
      float pcv  = sigm((mid-est)*64.f);
      float ncv  = sigm((mid+est)*64.f);
      a_c = clampf((pcv-ncv+1e-5f)/(pcv+1e-5f), 0.f, 1.f);
      qv  = 1.f - a_c + 1e-7f;
    }
    float p = qv;
    #pragma unroll
    for (int off = 1; off < 64; off <<= 1){
      float t = __shfl_up(p, off);
      if (lane >= off) p *= t;
    }
    float ec = __shfl_up(p, 1);
    if (lane == 0) ec = 1.f;
    float wvv = (lane < 63) ? (a_c*ec + 1e-5f) : 0.f;
    float tot = wvv;
    #pragma unroll
    for (int off = 32; off > 0; off >>= 1) tot += __shfl_xor(tot, off);
    float cs = wvv;
    #pragma unroll
    for (int off = 1; off < 64; off <<= 1){
      float t = __shfl_up(cs, off);
      if (lane >= off) cs += t;
    }
    if (lane == 0)  s_cdf[rs][0] = 0.f;
    if (lane < 63)  s_cdf[rs][lane+1] = cs / tot;
  }
  __syncthreads();

  // ---- sample_pdf (searchsorted right + lerp) ----
  if (wir == 0){
    float u = ((float)lane + 0.5f) * (1.f/64.f);
    int lo = 0, hi = 64;
    while (lo < hi){
      int m = (lo+hi) >> 1;
      if (s_cdf[rs][m] <= u) lo = m+1; else hi = m;
    }
    int below = lo - 1;
    int above = lo < 63 ? lo : 63;
    float cb = s_cdf[rs][below], ca = s_cdf[rs][above];
    float bb = s_z[rs][below],   ba = s_z[rs][above];
    float den = ca - cb; if (den < 1e-5f) den = 1.f;
    float tt = (u - cb)/den;
    s_newz[rs][lane] = bb + tt*(ba - bb);
  }
  __syncthreads();

  // ---- parallel merge of two sorted 64-lists ----
  {
    float v; int pos;
    if (lt < 64){
      v = s_z[rs][lt];
      int lo = 0, hi = 64;
      while (lo < hi){ int m=(lo+hi)>>1; if (s_newz[rs][m] < v) lo = m+1; else hi = m; }
      pos = lt + lo;
    } else {
      int jj = lt - 64;
      v = s_newz[rs][jj];
      int lo = 0, hi = 64;
      while (lo < hi){ int m=(lo+hi)>>1; if (s_z[rs][m] <= v) lo = m+1; else hi = m; }
      pos = jj + lo;
    }
    s_zall[rs][pos] = v;
  }
  __syncthreads();

  // ---- fine pass ----
  float zc = s_zall[rs][lt];
  float zn = s_zall[rs][lt < 127 ? lt+1 : 127];
  float delta = (lt < 127) ? (zn - zc) : sd;
  float zm    = (lt < 127) ? (zc + 0.5f*delta) : zc;
  float px = clampf(ox + dx*zm, -1.f, 1.f);
  float py = clampf(oy + dy*zm, -1.f, 1.f);
  float pz = clampf(oz + dz*zm, -1.f, 1.f);

  // layer-1 + sdf col-0 + 6-point FD grad; hv -> LDS row (bf16 pairs)
  unsigned short* arow = &SU[wv*64*KS + (unsigned)lane * KS];
  float sa = b20;
  float a0=b20,a1=b20,a2=b20,a3=b20,a4=b20,a5=b20;
  #pragma unroll 2
  for (int j2 = 0; j2 < 32; ++j2){
    int j = 2*j2;
    float4 w0 = s_w1[j],   e0 = s_w1e[j];
    float4 w1 = s_w1[j+1], e1 = s_w1e[j+1];
    float base0 = fmaf(px, w0.x, fmaf(py, w0.y, fmaf(pz, w0.z, w0.w)));
    float base1 = fmaf(px, w1.x, fmaf(py, w1.y, fmaf(pz, w1.z, w1.w)));
    float hv0 = fmaxf(base0, 0.f), hv1 = fmaxf(base1, 0.f);
    sa = fmaf(hv0, e0.w, sa); sa = fmaf(hv1, e1.w, sa);
    a0 = fmaf(fmaxf(base0+e0.x,0.f), e0.w, a0); a0 = fmaf(fmaxf(base1+e1.x,0.f), e1.w, a0);
    a1 = fmaf(fmaxf(base0-e0.x,0.f), e0.w, a1); a1 = fmaf(fmaxf(base1-e1.x,0.f), e1.w, a1);
    a2 = fmaf(fmaxf(base0+e0.y,0.f), e0.w, a2); a2 = fmaf(fmaxf(base1+e1.y,0.f), e1.w, a2);
    a3 = fmaf(fmaxf(base0-e0.y,0.f), e0.w, a3); a3 = fmaf(fmaxf(base1-e1.y,0.f), e1.w, a3);
    a4 = fmaf(fmaxf(base0+e0.z,0.f), e0.w, a4); a4 = fmaf(fmaxf(base1+e1.z,0.f), e1.w, a4);
    a5 = fmaf(fmaxf(base0-e0.z,0.f), e0.w, a5); a5 = fmaf(fmaxf(base1-e1.z,0.f), e1.w, a5);
    *(unsigned*)&arow[j] = pk2(hv0, hv1);
  }
  float sdfv = sa;
  float gx = (a0-a1)*100.f, gy = (a2-a3)*100.f, gz = (a4-a5)*100.f;
  float gn = 1e-5f + sqrtf(gx*gx + gy*gy + gz*gz);
  float nx = gx/gn, ny = gy/gn, nz = gz/gn;

  // ext slots: k=64..72 = [pt,dir,n], k=73 = 1, k=74..79 = 0
  *(unsigned*)&arow[64] = pk2(px, py);
  *(unsigned*)&arow[66] = pk2(pz, dx);
  *(unsigned*)&arow[68] = pk2(dy, dz);
  *(unsigned*)&arow[70] = pk2(nx, ny);
  *(unsigned*)&arow[72] = pk2(nz, 1.0f);
  *(unsigned*)&arow[74] = 0u;
  *(unsigned*)&arow[76] = 0u;
  *(unsigned*)&arow[78] = 0u;

  __builtin_amdgcn_wave_barrier();   // keep ds writes above ds reads below

  // MFMA: C[c][s] = A(64x80) x aext^T(80x64)
  f32x16 acc00, acc01, acc10, acc11;
  #pragma unroll
  for (int i = 0; i < 16; ++i){ acc00[i]=0.f; acc01[i]=0.f; acc10[i]=0.f; acc11[i]=0.f; }
  const unsigned short* aw = &SU[wv*64*KS];
  const int scol = l31;
  #pragma unroll
  for (int kk = 0; kk < 5; ++kk){
    int koff = 16*kk + 8*h;
    short8v b0 = lds_load8(&aw[ scol      * KS + koff]);
    short8v b1 = lds_load8(&aw[(32+scol) * KS + koff]);
    acc00 = __builtin_amdgcn_mfma_f32_32x32x16_bf16(af[kk],   b0, acc00, 0, 0, 0);
    acc10 = __builtin_amdgcn_mfma_f32_32x32x16_bf16(af[5+kk], b0, acc10, 0, 0, 0);
    acc01 = __builtin_amdgcn_mfma_f32_32x32x16_bf16(af[kk],   b1, acc01, 0, 0, 0);
    acc11 = __builtin_amdgcn_mfma_f32_32x32x16_bf16(af[5+kk], b1, acc11, 0, 0, 0);
  }

  // relu -> *Wc2 -> reduce over c
  float pr0=0.f,pr1=0.f,pr2=0.f,pr3=0.f,pr4=0.f,pr5=0.f;
  const int halfoff = h * 4;
  #pragma unroll
  for (int r = 0; r < 16; ++r){
    int ci = (r & 3) + 8*(r >> 2) + halfoff;
    float4 wA = s_wc2[ci];
    float4 wB = s_wc2[32 + ci];
    float v;
    v = fmaxf(acc00[r], 0.f); pr0 = fmaf(v, wA.x, pr0); pr1 = fmaf(v, wA.y, pr1); pr2 = fmaf(v, wA.z, pr2);
    v = fmaxf(acc10[r], 0.f); pr0 = fmaf(v, wB.x, pr0); pr1 = fmaf(v, wB.y, pr1); pr2 = fmaf(v, wB.z, pr2);
    v = fmaxf(acc01[r], 0.f); pr3 = fmaf(v, wA.x, pr3); pr4 = fmaf(v, wA.y, pr4); pr5 = fmaf(v, wA.z, pr5);
    v = fmaxf(acc11[r], 0.f); pr3 = fmaf(v, wB.x, pr3); pr4 = fmaf(v, wB.y, pr4); pr5 = fmaf(v, wB.z, pr5);
  }
  pr0 += __shfl_xor(pr0, 32); pr1 += __shfl_xor(pr1, 32); pr2 += __shfl_xor(pr2, 32);
  pr3 += __shfl_xor(pr3, 32); pr4 += __shfl_xor(pr4, 32); pr5 += __shfl_xor(pr5, 32);
  const bool hihalf = (lane >= 32);
  float c0 = sigm((hihalf ? pr3 : pr0) + bc2[0]);
  float c1 = sigm((hihalf ? pr4 : pr1) + bc2[1]);
  float c2 = sigm((hihalf ? pr5 : pr2) + bc2[2]);

  // NeuS alpha (fp32 path)
  const float inv_s = expf(10.f * inv_s_p[0]);
  float tcos = dx*nx + dy*ny + dz*nz;
  float aarg = -100.f * tcos;
  float spv  = (aarg > 0.f) ? (aarg + log1pf(expf(-aarg))) : log1pf(expf(aarg));
  float iter_cos = -(spv * 0.01f);
  float est = iter_cos * delta * 0.5f;
  float pcv = sigm((sdfv - est)*inv_s);
  float ncv = sigm((sdfv + est)*inv_s);
  float alpha = clampf((pcv - ncv + 1e-5f)/(pcv + 1e-5f), 0.f, 1.f);

  // transmittance scan over 128 samples (2 waves) + composite
  float qv = 1.f - alpha + 1e-7f;
  float p = qv;
  #pragma unroll
  for (int off = 1; off < 64; off <<= 1){
    float t = __shfl_up(p, off);
    if (lane >= off) p *= t;
  }
  if (lane == 63) s_wtot[rs][wir] = p;
  __syncthreads();
  float excl = __shfl_up(p, 1);
  if (lane == 0) excl = 1.f;
  if (wir == 1) excl *= s_wtot[rs][0];
  float w  = alpha * excl;
  float r0 = w, r1 = w*c0, r2 = w*c1, r3 = w*c2;
  #pragma unroll
  for (int off = 32; off > 0; off >>= 1){
    r0 += __shfl_xor(r0, off);
    r1 += __shfl_xor(r1, off);
    r2 += __shfl_xor(r2, off);
    r3 += __shfl_xor(r3, off);
  }
  if (lane == 0){
    s_red[rs][wir][0]=r0; s_red[rs][wir][1]=r1; s_red[rs][wir][2]=r2; s_red[rs][wir][3]=r3;
  }
  __syncthreads();
  if (lt == 0){
    float wsum = s_red[rs][0][0] + s_red[rs][1][0];
    float bg = 1.f - wsum;
    out[ray*3+0] = s_red[rs][0][1] + s_red[rs][1][1] + bg;
    out[ray*3+1] = s_red[rs][0][2] + s_red[rs][1][2] + bg;
    out[ray*3+2] = s_red[rs][0][3] + s_red[rs][1][3] + bg;
  }
}

extern "C" void kernel_launch(void* const* d_in, const int* in_sizes, int n_in,
                              void* d_out, int out_size, void* d_ws, size_t ws_size,
                              hipStream_t stream)
{
  const float* rays_o = (const float*)d_in[0];
  const float* rays_d = (const float*)d_in[1];
  const float* W1  = (const float*)d_in[2];
  const float* b1  = (const float*)d_in[3];
  const float* W2  = (const float*)d_in[4];
  const float* b2  = (const float*)d_in[5];
  const float* Wc1 = (const float*)d_in[6];
  const float* bc1 = (const float*)d_in[7];
  const float* Wc2 = (const float*)d_in[8];
  const float* bc2 = (const float*)d_in[9];
  const float* inv_s = (const float*)d_in[10];
  float* out = (float*)d_out;

  const int R = in_sizes[0] / 3;               // 4096 rays
  dim3 grid(R / RAYS_PER_BLOCK), block(256);
  neus_render<<<grid, block, 0, stream>>>(rays_o, rays_d, W1, b1, W2, b2,
                                          Wc1, bc1, Wc2, bc2, inv_s, out);
}

// Round 7
// 130.752 us; speedup vs baseline: 1.1553x; 1.1553x over previous
//
#include <hip/hip_runtime.h>
#include <hip/hip_bf16.h>
#include <cmath>

#define RAYS_PER_BLOCK 2
#define KS 84   // aext row stride in ushorts (bank-decorrelated, 8B-aligned rows)

// ---- packed-weight layout in d_ws (float offsets) ----
#define OFF_W1    0      // 64 x float4 {W1[0][j],W1[1][j],W1[2][j],b1[j]}
#define OFF_W1E   256    // 64 x float4 {2e|W1x|, 2e|W1y|, 2e|W1z|, W2[j][0]}
#define OFF_W1S   512    // 64 x float4 {W2j*sgn(W1x), W2j*sgn(W1y), W2j*sgn(W1z), 0}
#define OFF_WC2   768    // 64 x float4 {Wc2[c][0..2], 0}
#define OFF_BC2   1024   // {bc2[0],bc2[1],bc2[2], b2[0]}
#define OFF_AF    1028   // 10 frags x 64 lanes x 8 bf16, A-operand-swizzled (16B/lane/frag)

typedef __attribute__((ext_vector_type(4))) short  short4v;
typedef __attribute__((ext_vector_type(8))) short  short8v;
typedef __attribute__((ext_vector_type(16))) float f32x16;

__device__ __forceinline__ float sigm(float x){ return 1.0f/(1.0f + expf(-x)); }
__device__ __forceinline__ float clampf(float x, float lo, float hi){ return fminf(fmaxf(x, lo), hi); }
__device__ __forceinline__ unsigned short f2bf(float x){
  __hip_bfloat16 h = __float2bfloat16(x);
  return *reinterpret_cast<unsigned short*>(&h);
}
__device__ __forceinline__ unsigned pk2(float a, float b){
  return (unsigned)f2bf(a) | ((unsigned)f2bf(b) << 16);
}
__device__ __forceinline__ short8v lds_load8(const unsigned short* p){
  short4v lo = *(const short4v*)p;
  short4v hi = *(const short4v*)(p + 4);
  short8v r;
  r[0]=lo[0]; r[1]=lo[1]; r[2]=lo[2]; r[3]=lo[3];
  r[4]=hi[0]; r[5]=hi[1]; r[6]=hi[2]; r[7]=hi[3];
  return r;
}

// A[c][k]: k<64 -> M[k][c]=sum_t W2[k][1+t]*Wc1[9+t][c]; k=64..72 -> Wc1[k-64][c];
// k=73 -> cb[c]=bc1[c]+sum_t b2[1+t]*Wc1[9+t][c]; k>=74 -> 0.
// LDS-staged: W2/Wc1 read once coalesced into LDS, dots run from LDS (broadcast-friendly).
__global__ __launch_bounds__(256)
void prep_weights(const float* __restrict__ W1, const float* __restrict__ b1,
                  const float* __restrict__ W2, const float* __restrict__ b2,
                  const float* __restrict__ Wc1, const float* __restrict__ bc1,
                  const float* __restrict__ Wc2, const float* __restrict__ bc2,
                  float* __restrict__ ws)
{
  __shared__ float sWc1[64*64];  // [t][c] = Wc1[(9+t)*64 + c]
  __shared__ float sW2[64*64];   // [k][t] = W2[k*65 + 1 + t]
  __shared__ float sB2[64];      // b2[1+t]
  const int tid = threadIdx.x;
  for (int i = tid; i < 4096; i += 256){
    int r = i >> 6, c = i & 63;
    sWc1[i] = Wc1[(9+r)*64 + c];
    sW2[i]  = W2[r*65 + 1 + c];
  }
  if (tid < 64) sB2[tid] = b2[1+tid];
  __syncthreads();

  int g = blockIdx.x * 256 + tid;
  if (g < 640){                       // A-fragment swizzle: frag f=(mb*5+kk), lane ln
    int f = g >> 6, ln = g & 63;
    int mb = f / 5, kk = f - 5*mb;
    int c  = 32*mb + (ln & 31);
    int kbase = 16*kk + 8*(ln >> 5);
    unsigned short* dst = ((unsigned short*)(ws + OFF_AF)) + (size_t)g * 8;
    if (kk < 4){
      float acc[8];
      #pragma unroll
      for (int j = 0; j < 8; ++j) acc[j] = 0.f;
      for (int t = 0; t < 64; ++t){
        float wv = sWc1[t*64 + c];
        #pragma unroll
        for (int j = 0; j < 8; ++j) acc[j] += sW2[(kbase+j)*64 + t] * wv;
      }
      #pragma unroll
      for (int j = 0; j < 8; ++j) dst[j] = f2bf(acc[j]);
    } else {
      for (int j = 0; j < 8; ++j){
        int k = kbase + j;
        float v;
        if (k < 73){
          v = Wc1[(k-64)*64 + c];
        } else if (k == 73){
          v = bc1[c];
          for (int t = 0; t < 64; ++t) v += sB2[t] * sWc1[t*64 + c];
        } else v = 0.f;
        dst[j] = f2bf(v);
      }
    }
  } else if (g < 704){                // W1 pack
    int j = g - 640;
    ws[OFF_W1 + 4*j + 0] = W1[j];
    ws[OFF_W1 + 4*j + 1] = W1[64+j];
    ws[OFF_W1 + 4*j + 2] = W1[128+j];
    ws[OFF_W1 + 4*j + 3] = b1[j];
  } else if (g < 768){                // W1E pack: {2eps*|w|, w2c0}
    int j = g - 704;
    ws[OFF_W1E + 4*j + 0] = 0.01f * fabsf(W1[j]);
    ws[OFF_W1E + 4*j + 1] = 0.01f * fabsf(W1[64+j]);
    ws[OFF_W1E + 4*j + 2] = 0.01f * fabsf(W1[128+j]);
    ws[OFF_W1E + 4*j + 3] = W2[j*65];
  } else if (g < 832){                // W1S pack: {w2c0 * sgn(w)}
    int j = g - 768;
    float w2 = W2[j*65];
    ws[OFF_W1S + 4*j + 0] = (W1[j]     < 0.f) ? -w2 : w2;
    ws[OFF_W1S + 4*j + 1] = (W1[64+j]  < 0.f) ? -w2 : w2;
    ws[OFF_W1S + 4*j + 2] = (W1[128+j] < 0.f) ? -w2 : w2;
    ws[OFF_W1S + 4*j + 3] = 0.f;
  } else if (g < 896){                // Wc2 pack
    int j = g - 832;
    ws[OFF_WC2 + 4*j + 0] = Wc2[j*3+0];
    ws[OFF_WC2 + 4*j + 1] = Wc2[j*3+1];
    ws[OFF_WC2 + 4*j + 2] = Wc2[j*3+2];
    ws[OFF_WC2 + 4*j + 3] = 0.f;
  } else if (g < 900){                // bc2 + b2[0]
    int j = g - 896;
    ws[OFF_BC2 + j] = (j < 3) ? bc2[j] : b2[0];
  }
}

// One block = 2 rays x 128 threads; thread lt = fine sample; wave = 64 samples.
__global__ __launch_bounds__(256)
void neus_render(const float* __restrict__ rays_o, const float* __restrict__ rays_d,
                 const float* __restrict__ inv_s_p, const float* __restrict__ ws,
                 float* __restrict__ out)
{
  __shared__ unsigned short s_aext[4][64*KS];   // per-wave activation rows (bf16)
  __shared__ float4 s_wc2[64];
  __shared__ float  s_z[RAYS_PER_BLOCK][64];
  __shared__ float  s_cdf[RAYS_PER_BLOCK][64];
  __shared__ float  s_newz[RAYS_PER_BLOCK][64];
  __shared__ float  s_zall[RAYS_PER_BLOCK][128];
  __shared__ float  s_red[RAYS_PER_BLOCK][2][4];
  __shared__ float  s_wtot[RAYS_PER_BLOCK][2];

  const int tid  = threadIdx.x;
  const int rs   = tid >> 7;
  const int lt   = tid & 127;
  const int lane = tid & 63;
  const int wir  = (tid >> 6) & 1;
  const int wv   = tid >> 6;
  const int ray  = blockIdx.x * RAYS_PER_BLOCK + rs;

  const float4* __restrict__ pW1  = (const float4*)(ws + OFF_W1);
  const float4* __restrict__ pW1E = (const float4*)(ws + OFF_W1E);
  const float4* __restrict__ pW1S = (const float4*)(ws + OFF_W1S);
  const float*  __restrict__ pbc2 = ws + OFF_BC2;
  const float b20 = pbc2[3];

  if (tid < 64) s_wc2[tid] = ((const float4*)(ws + OFF_WC2))[tid];

  // ---- per-ray setup ----
  float ox = rays_o[ray*3], oy = rays_o[ray*3+1], oz = rays_o[ray*3+2];
  float dx = rays_d[ray*3], dy = rays_d[ray*3+1], dz = rays_d[ray*3+2];
  float tnx = (-1.f-ox)/(dx+1e-15f), tfx = (1.f-ox)/(dx+1e-15f);
  float tny = (-1.f-oy)/(dy+1e-15f), tfy = (1.f-oy)/(dy+1e-15f);
  float tnz = (-1.f-oz)/(dz+1e-15f), tfz = (1.f-oz)/(dz+1e-15f);
  float nearv = fmaxf(fmaxf(fminf(tnx,tfx), fminf(tny,tfy)), fminf(tnz,tfz));
  float farv  = fminf(fminf(fmaxf(tnx,tfx), fmaxf(tny,tfy)), fmaxf(tnz,tfz));
  nearv = fmaxf(nearv, 0.05f);
  const float sd = (farv - nearv) * (1.f/64.f);

  // ---- coarse pass: wave 0 of each ray (lane = coarse sample) ----
  if (wir == 0){
    float zt = nearv + (farv-nearv) * ((float)lane * (1.f/63.f));
    float px = clampf(ox + dx*zt, -1.f, 1.f);
    float py = clampf(oy + dy*zt, -1.f, 1.f);
    float pz = clampf(oz + dz*zt, -1.f, 1.f);
    float acc = b20;
    #pragma unroll 8
    for (int j = 0; j < 64; ++j){
      float4 w = pW1[j];
      acc += fmaxf(px*w.x + py*w.y + pz*w.z + w.w, 0.f) * ws[OFF_W1E + 4*j + 3];
    }
    s_z[rs][lane] = zt;
    float s1  = __shfl_down(acc, 1);
    float zt1 = nearv + (farv-nearv) * ((float)(lane+1) * (1.f/63.f));
    float a_c = 0.f, qv = 1.f;
    if (lane < 63){
      float dc   = zt1 - zt;
      float mid  = 0.5f*(acc + s1);
      float cosv = clampf((s1-acc)/(dc+1e-5f), -1000.f, 0.f);
      float est  = cosv*dc*0.5f;
      float pcv  = sigm((mid-est)*64.f);
      float ncv  = sigm((mid+est)*64.f);
      a_c = clampf((pcv-ncv+1e-5f)/(pcv+1e-5f), 0.f, 1.f);
      qv  = 1.f - a_c + 1e-7f;
    }
    float p = qv;
    #pragma unroll
    for (int off = 1; off < 64; off <<= 1){
      float t = __shfl_up(p, off);
      if (lane >= off) p *= t;
    }
    float ec = __shfl_up(p, 1);
    if (lane == 0) ec = 1.f;
    float wvv = (lane < 63) ? (a_c*ec + 1e-5f) : 0.f;
    float tot = wvv;
    #pragma unroll
    for (int off = 32; off > 0; off >>= 1) tot += __shfl_xor(tot, off);
    float cs = wvv;
    #pragma unroll
    for (int off = 1; off < 64; off <<= 1){
      float t = __shfl_up(cs, off);
      if (lane >= off) cs += t;
    }
    if (lane == 0)  s_cdf[rs][0] = 0.f;
    if (lane < 63)  s_cdf[rs][lane+1] = cs / tot;
  }
  __syncthreads();

  // ---- sample_pdf (searchsorted right + lerp) ----
  if (wir == 0){
    float u = ((float)lane + 0.5f) * (1.f/64.f);
    int lo = 0, hi = 64;
    while (lo < hi){
      int m = (lo+hi) >> 1;
      if (s_cdf[rs][m] <= u) lo = m+1; else hi = m;
    }
    int below = lo - 1;
    int above = lo < 63 ? lo : 63;
    float cb = s_cdf[rs][below], ca = s_cdf[rs][above];
    float bb = s_z[rs][below],   ba = s_z[rs][above];
    float den = ca - cb; if (den < 1e-5f) den = 1.f;
    float tt = (u - cb)/den;
    s_newz[rs][lane] = bb + tt*(ba - bb);
  }
  __syncthreads();

  // A-fragments (weights, pre-swizzled bf16) — issue early to overlap latency
  const short8v* pAF = (const short8v*)(ws + OFF_AF);
  short8v af[10];
  #pragma unroll
  for (int f = 0; f < 10; ++f) af[f] = pAF[f*64 + lane];

  // ---- parallel merge of two sorted 64-lists ----
  {
    float v; int pos;
    if (lt < 64){
      v = s_z[rs][lt];
      int lo = 0, hi = 64;
      while (lo < hi){ int m=(lo+hi)>>1; if (s_newz[rs][m] < v) lo = m+1; else hi = m; }
      pos = lt + lo;
    } else {
      int jj = lt - 64;
      v = s_newz[rs][jj];
      int lo = 0, hi = 64;
      while (lo < hi){ int m=(lo+hi)>>1; if (s_z[rs][m] <= v) lo = m+1; else hi = m; }
      pos = jj + lo;
    }
    s_zall[rs][pos] = v;
  }
  __syncthreads();

  // ---- fine pass ----
  float zc = s_zall[rs][lt];
  float zn = s_zall[rs][lt < 127 ? lt+1 : 127];
  float delta = (lt < 127) ? (zn - zc) : sd;
  float zm    = (lt < 127) ? (zc + 0.5f*delta) : zc;
  float px = clampf(ox + dx*zm, -1.f, 1.f);
  float py = clampf(oy + dy*zm, -1.f, 1.f);
  float pz = clampf(oz + dz*zm, -1.f, 1.f);

  // layer-1 + sdf col-0 + FD grad via med3 identity:
  // relu(b+ew)-relu(b-ew) = sgn(w)*med3(b+e|w|, 0, 2e|w|)
  unsigned short* arow = &s_aext[wv][(unsigned)lane * KS];
  float sa = b20;
  float gxa = 0.f, gya = 0.f, gza = 0.f;
  #pragma unroll 2
  for (int j2 = 0; j2 < 32; ++j2){
    int j = 2*j2;
    float4 w0 = pW1[j],   e0 = pW1E[j],   s0 = pW1S[j];
    float4 w1 = pW1[j+1], e1 = pW1E[j+1], s1v = pW1S[j+1];
    float base0 = fmaf(px, w0.x, fmaf(py, w0.y, fmaf(pz, w0.z, w0.w)));
    float base1 = fmaf(px, w1.x, fmaf(py, w1.y, fmaf(pz, w1.z, w1.w)));
    float hv0 = fmaxf(base0, 0.f), hv1 = fmaxf(base1, 0.f);
    sa = fmaf(hv0, e0.w, sa); sa = fmaf(hv1, e1.w, sa);
    gxa = fmaf(__builtin_amdgcn_fmed3f(fmaf(0.5f, e0.x, base0), 0.f, e0.x), s0.x, gxa);
    gya = fmaf(__builtin_amdgcn_fmed3f(fmaf(0.5f, e0.y, base0), 0.f, e0.y), s0.y, gya);
    gza = fmaf(__builtin_amdgcn_fmed3f(fmaf(0.5f, e0.z, base0), 0.f, e0.z), s0.z, gza);
    gxa = fmaf(__builtin_amdgcn_fmed3f(fmaf(0.5f, e1.x, base1), 0.f, e1.x), s1v.x, gxa);
    gya = fmaf(__builtin_amdgcn_fmed3f(fmaf(0.5f, e1.y, base1), 0.f, e1.y), s1v.y, gya);
    gza = fmaf(__builtin_amdgcn_fmed3f(fmaf(0.5f, e1.z, base1), 0.f, e1.z), s1v.z, gza);
    *(unsigned*)&arow[j] = pk2(hv0, hv1);
  }
  float sdfv = sa;
  float gx = gxa*100.f, gy = gya*100.f, gz = gza*100.f;
  float gn = 1e-5f + sqrtf(gx*gx + gy*gy + gz*gz);
  float nx = gx/gn, ny = gy/gn, nz = gz/gn;

  // ext slots: k=64..72 = [pt,dir,n], k=73 = 1, k=74..79 = 0
  *(unsigned*)&arow[64] = pk2(px, py);
  *(unsigned*)&arow[66] = pk2(pz, dx);
  *(unsigned*)&arow[68] = pk2(dy, dz);
  *(unsigned*)&arow[70] = pk2(nx, ny);
  *(unsigned*)&arow[72] = pk2(nz, 1.0f);
  *(unsigned*)&arow[74] = 0u;
  *(unsigned*)&arow[76] = 0u;
  *(unsigned*)&arow[78] = 0u;

  __builtin_amdgcn_wave_barrier();   // keep ds writes above ds reads below

  // MFMA: C[c][s] = A(64x80) x aext^T(80x64), tiles (mb over c, nb over s)
  f32x16 acc00, acc01, acc10, acc11;
  #pragma unroll
  for (int i = 0; i < 16; ++i){ acc00[i]=0.f; acc01[i]=0.f; acc10[i]=0.f; acc11[i]=0.f; }
  const unsigned short* aw = s_aext[wv];
  const int scol = lane & 31;
  const int half8 = (lane >> 5) * 8;
  #pragma unroll
  for (int kk = 0; kk < 5; ++kk){
    int koff = 16*kk + half8;
    short8v b0 = lds_load8(&aw[ scol      * KS + koff]);
    short8v b1 = lds_load8(&aw[(32+scol) * KS + koff]);
    acc00 = __builtin_amdgcn_mfma_f32_32x32x16_bf16(af[kk],   b0, acc00, 0, 0, 0);
    acc10 = __builtin_amdgcn_mfma_f32_32x32x16_bf16(af[5+kk], b0, acc10, 0, 0, 0);
    acc01 = __builtin_amdgcn_mfma_f32_32x32x16_bf16(af[kk],   b1, acc01, 0, 0, 0);
    acc11 = __builtin_amdgcn_mfma_f32_32x32x16_bf16(af[5+kk], b1, acc11, 0, 0, 0);
  }

  // relu -> *Wc2 -> reduce over c: in-lane over regs, cross-half via shfl_xor(32)
  float pr0=0.f,pr1=0.f,pr2=0.f,pr3=0.f,pr4=0.f,pr5=0.f;
  const int halfoff = (lane >> 5) * 4;
  #pragma unroll
  for (int r = 0; r < 16; ++r){
    int ci = (r & 3) + 8*(r >> 2) + halfoff;
    float4 wA = s_wc2[ci];
    float4 wB = s_wc2[32 + ci];
    float v;
    v = fmaxf(acc00[r], 0.f); pr0 = fmaf(v, wA.x, pr0); pr1 = fmaf(v, wA.y, pr1); pr2 = fmaf(v, wA.z, pr2);
    v = fmaxf(acc10[r], 0.f); pr0 = fmaf(v, wB.x, pr0); pr1 = fmaf(v, wB.y, pr1); pr2 = fmaf(v, wB.z, pr2);
    v = fmaxf(acc01[r], 0.f); pr3 = fmaf(v, wA.x, pr3); pr4 = fmaf(v, wA.y, pr4); pr5 = fmaf(v, wA.z, pr5);
    v = fmaxf(acc11[r], 0.f); pr3 = fmaf(v, wB.x, pr3); pr4 = fmaf(v, wB.y, pr4); pr5 = fmaf(v, wB.z, pr5);
  }
  pr0 += __shfl_xor(pr0, 32); pr1 += __shfl_xor(pr1, 32); pr2 += __shfl_xor(pr2, 32);
  pr3 += __shfl_xor(pr3, 32); pr4 += __shfl_xor(pr4, 32); pr5 += __shfl_xor(pr5, 32);
  const bool hihalf = (lane >= 32);
  float c0 = sigm((hihalf ? pr3 : pr0) + pbc2[0]);
  float c1 = sigm((hihalf ? pr4 : pr1) + pbc2[1]);
  float c2 = sigm((hihalf ? pr5 : pr2) + pbc2[2]);

  // NeuS alpha (fp32 path, unchanged)
  const float inv_s = expf(10.f * inv_s_p[0]);
  float tcos = dx*nx + dy*ny + dz*nz;
  float aarg = -100.f * tcos;
  float spv  = (aarg > 0.f) ? (aarg + log1pf(expf(-aarg))) : log1pf(expf(aarg));
  float iter_cos = -(spv * 0.01f);
  float est = iter_cos * delta * 0.5f;
  float pcv = sigm((sdfv - est)*inv_s);
  float ncv = sigm((sdfv + est)*inv_s);
  float alpha = clampf((pcv - ncv + 1e-5f)/(pcv + 1e-5f), 0.f, 1.f);

  // transmittance scan over 128 samples (2 waves) + composite
  float qv = 1.f - alpha + 1e-7f;
  float p = qv;
  #pragma unroll
  for (int off = 1; off < 64; off <<= 1){
    float t = __shfl_up(p, off);
    if (lane >= off) p *= t;
  }
  if (lane == 63) s_wtot[rs][wir] = p;
  __syncthreads();
  float excl = __shfl_up(p, 1);
  if (lane == 0) excl = 1.f;
  if (wir == 1) excl *= s_wtot[rs][0];
  float w  = alpha * excl;
  float r0 = w, r1 = w*c0, r2 = w*c1, r3 = w*c2;
  #pragma unroll
  for (int off = 32; off > 0; off >>= 1){
    r0 += __shfl_xor(r0, off);
    r1 += __shfl_xor(r1, off);
    r2 += __shfl_xor(r2, off);
    r3 += __shfl_xor(r3, off);
  }
  if (lane == 0){
    s_red[rs][wir][0]=r0; s_red[rs][wir][1]=r1; s_red[rs][wir][2]=r2; s_red[rs][wir][3]=r3;
  }
  __syncthreads();
  if (lt == 0){
    float wsum = s_red[rs][0][0] + s_red[rs][1][0];
    float bg = 1.f - wsum;
    out[ray*3+0] = s_red[rs][0][1] + s_red[rs][1][1] + bg;
    out[ray*3+1] = s_red[rs][0][2] + s_red[rs][1][2] + bg;
    out[ray*3+2] = s_red[rs][0][3] + s_red[rs][1][3] + bg;
  }
}

extern "C" void kernel_launch(void* const* d_in, const int* in_sizes, int n_in,
                              void* d_out, int out_size, void* d_ws, size_t ws_size,
                              hipStream_t stream)
{
  const float* rays_o = (const float*)d_in[0];
  const float* rays_d = (const float*)d_in[1];
  const float* W1  = (const float*)d_in[2];
  const float* b1  = (const float*)d_in[3];
  const float* W2  = (const float*)d_in[4];
  const float* b2  = (const float*)d_in[5];
  const float* Wc1 = (const float*)d_in[6];
  const float* bc1 = (const float*)d_in[7];
  const float* Wc2 = (const float*)d_in[8];
  const float* bc2 = (const float*)d_in[9];
  const float* inv_s = (const float*)d_in[10];
  float* out = (float*)d_out;
  float* ws  = (float*)d_ws;

  prep_weights<<<4, 256, 0, stream>>>(W1, b1, W2, b2, Wc1, bc1, Wc2, bc2, ws);

  const int R = in_sizes[0] / 3;               // 4096 rays
  dim3 grid(R / RAYS_PER_BLOCK), block(256);
  neus_render<<<grid, block, 0, stream>>>(rays_o, rays_d, inv_s, ws, out);
}

// Round 8
// 129.850 us; speedup vs baseline: 1.1633x; 1.0069x over previous
//
#include <hip/hip_runtime.h>
#include <hip/hip_bf16.h>
#include <cmath>

#define RAYS_PER_BLOCK 2
#define KS 84   // row stride in ushorts (bank-decorrelated, 8B-aligned rows)

// ---- packed-weight layout in d_ws (float offsets) ----
#define OFF_W1    0      // 64 x float4 {W1[0][j],W1[1][j],W1[2][j],b1[j]}
#define OFF_W1E   256    // 64 x float4 {2e|W1x|, 2e|W1y|, 2e|W1z|, W2[j][0]}
#define OFF_W1S   512    // 64 x float4 {W2j*sgn(W1x), W2j*sgn(W1y), W2j*sgn(W1z), 0}
#define OFF_WC2   768    // 64 x float4 {Wc2[c][0..2], 0}
#define OFF_BC2   1024   // {bc2[0],bc2[1],bc2[2], b2[0]}
#define OFF_AF    1028   // 10 frags x 64 lanes x 8 bf16, A-operand-swizzled (16B/lane/frag)

typedef __attribute__((ext_vector_type(4))) short  short4v;
typedef __attribute__((ext_vector_type(8))) short  short8v;
typedef __attribute__((ext_vector_type(16))) float f32x16;

__device__ __forceinline__ float sigm(float x){ return 1.0f/(1.0f + expf(-x)); }
__device__ __forceinline__ float clampf(float x, float lo, float hi){ return fminf(fmaxf(x, lo), hi); }
__device__ __forceinline__ unsigned short f2bf(float x){
  __hip_bfloat16 h = __float2bfloat16(x);
  return *reinterpret_cast<unsigned short*>(&h);
}
__device__ __forceinline__ unsigned pk2(float a, float b){
  return (unsigned)f2bf(a) | ((unsigned)f2bf(b) << 16);
}
__device__ __forceinline__ short8v lds_load8(const unsigned short* p){
  short4v lo = *(const short4v*)p;
  short4v hi = *(const short4v*)(p + 4);
  short8v r;
  r[0]=lo[0]; r[1]=lo[1]; r[2]=lo[2]; r[3]=lo[3];
  r[4]=hi[0]; r[5]=hi[1]; r[6]=hi[2]; r[7]=hi[3];
  return r;
}

// Prep (1 block, 256 threads): A[c][k] built in LDS via MFMA (M-tile per wave),
// ext rows/cb filled data-parallel, then the 10 pre-swizzled A-fragments
// extracted to ws. Small packs (W1/W1E/W1S/Wc2/bc2) by spare threads.
__global__ __launch_bounds__(256)
void prep_weights(const float* __restrict__ W1, const float* __restrict__ b1,
                  const float* __restrict__ W2, const float* __restrict__ b2,
                  const float* __restrict__ Wc1, const float* __restrict__ bc1,
                  const float* __restrict__ Wc2, const float* __restrict__ bc2,
                  float* __restrict__ ws)
{
  __shared__ unsigned short W2T[64*KS];   // [k][t] = W2[k][1+t] bf16
  __shared__ unsigned short ABUF[64*KS];  // A[c][k] bf16
  const int tid  = threadIdx.x;
  const int lane = tid & 63;
  const int wv   = tid >> 6;
  const int l31  = lane & 31;
  const int h    = lane >> 5;

  // stage W2[:,1:65] -> W2T (coalesced)
  for (int i = tid; i < 4096; i += 256){
    int k = i >> 6, t = i & 63;
    W2T[k*KS + t] = f2bf(W2[k*65 + 1 + t]);
  }
  // ext rows k=64..72: Wc1 rows 0..8
  for (int i = tid; i < 576; i += 256){
    int ii = i >> 6, c = i & 63;
    ABUF[c*KS + 64 + ii] = f2bf(Wc1[ii*64 + c]);
  }
  // zeros k=74..79
  for (int i = tid; i < 384; i += 256){
    int z = i >> 6, c = i & 63;
    ABUF[c*KS + 74 + z] = 0;
  }
  // cb row (k=73): wave 3, lane = c
  if (wv == 3){
    float acc = bc1[lane];
    #pragma unroll 4
    for (int t = 0; t < 64; ++t) acc = fmaf(b2[1+t], Wc1[(9+t)*64 + lane], acc);
    ABUF[lane*KS + 73] = f2bf(acc);
  }
  // small packs
  if (tid < 64){
    int j = tid;
    float wx = W1[j], wy = W1[64+j], wz = W1[128+j];
    float w2 = W2[j*65];
    ws[OFF_W1 + 4*j + 0] = wx;
    ws[OFF_W1 + 4*j + 1] = wy;
    ws[OFF_W1 + 4*j + 2] = wz;
    ws[OFF_W1 + 4*j + 3] = b1[j];
    ws[OFF_W1E + 4*j + 0] = 0.01f * fabsf(wx);
    ws[OFF_W1E + 4*j + 1] = 0.01f * fabsf(wy);
    ws[OFF_W1E + 4*j + 2] = 0.01f * fabsf(wz);
    ws[OFF_W1E + 4*j + 3] = w2;
    ws[OFF_W1S + 4*j + 0] = (wx < 0.f) ? -w2 : w2;
    ws[OFF_W1S + 4*j + 1] = (wy < 0.f) ? -w2 : w2;
    ws[OFF_W1S + 4*j + 2] = (wz < 0.f) ? -w2 : w2;
    ws[OFF_W1S + 4*j + 3] = 0.f;
  } else if (tid < 128){
    int j = tid - 64;
    ws[OFF_WC2 + 4*j + 0] = Wc2[j*3+0];
    ws[OFF_WC2 + 4*j + 1] = Wc2[j*3+1];
    ws[OFF_WC2 + 4*j + 2] = Wc2[j*3+2];
    ws[OFF_WC2 + 4*j + 3] = 0.f;
  } else if (tid < 132){
    int j = tid - 128;
    ws[OFF_BC2 + j] = (j < 3) ? bc2[j] : b2[0];
  }
  __syncthreads();

  // per-wave MFMA tile of E[c][k] = sum_t Wc1[9+t][c] * W2[k][1+t]
  {
    const int mb = wv & 1, kb = wv >> 1;
    f32x16 e;
    #pragma unroll
    for (int i = 0; i < 16; ++i) e[i] = 0.f;
    #pragma unroll
    for (int s = 0; s < 4; ++s){
      short8v afr;
      #pragma unroll
      for (int j = 0; j < 8; ++j)
        afr[j] = (short)f2bf(Wc1[(9 + 16*s + 8*h + j)*64 + 32*mb + l31]);
      short8v bfr = lds_load8(&W2T[(32*kb + l31)*KS + 16*s + 8*h]);
      e = __builtin_amdgcn_mfma_f32_32x32x16_bf16(afr, bfr, e, 0, 0, 0);
    }
    const int kcol = 32*kb + l31;
    #pragma unroll
    for (int r = 0; r < 16; ++r){
      int c = 32*mb + (r & 3) + 8*(r >> 2) + 4*h;
      ABUF[c*KS + kcol] = f2bf(e[r]);
    }
  }
  __syncthreads();

  // extract pre-swizzled A-fragments -> ws
  for (int i = tid; i < 640; i += 256){
    int f = i >> 6, ln = i & 63;
    int mb = f / 5, kk = f - 5*mb;
    int c  = 32*mb + (ln & 31);
    int kb2 = 16*kk + 8*(ln >> 5);
    short8v v = lds_load8(&ABUF[c*KS + kb2]);
    *((short8v*)(((unsigned short*)(ws + OFF_AF)) + (size_t)i * 8)) = v;
  }
}

// One block = 2 rays x 128 threads; thread lt = fine sample; wave = 64 samples.
__global__ __launch_bounds__(256)
void neus_render(const float* __restrict__ rays_o, const float* __restrict__ rays_d,
                 const float* __restrict__ inv_s_p, const float* __restrict__ ws,
                 float* __restrict__ out)
{
  __shared__ unsigned short s_aext[4][64*KS];   // per-wave activation rows (bf16)
  __shared__ float4 s_wc2[64];
  __shared__ float  s_z[RAYS_PER_BLOCK][64];
  __shared__ float  s_cdf[RAYS_PER_BLOCK][64];
  __shared__ float  s_newz[RAYS_PER_BLOCK][64];
  __shared__ float  s_zall[RAYS_PER_BLOCK][128];
  __shared__ float  s_red[RAYS_PER_BLOCK][2][4];
  __shared__ float  s_wtot[RAYS_PER_BLOCK][2];

  const int tid  = threadIdx.x;
  const int rs   = tid >> 7;
  const int lt   = tid & 127;
  const int lane = tid & 63;
  const int wir  = (tid >> 6) & 1;
  const int wv   = tid >> 6;
  const int ray  = blockIdx.x * RAYS_PER_BLOCK + rs;

  const float4* __restrict__ pW1  = (const float4*)(ws + OFF_W1);
  const float4* __restrict__ pW1E = (const float4*)(ws + OFF_W1E);
  const float4* __restrict__ pW1S = (const float4*)(ws + OFF_W1S);
  const float*  __restrict__ pbc2 = ws + OFF_BC2;
  const float b20 = pbc2[3];

  if (tid < 64) s_wc2[tid] = ((const float4*)(ws + OFF_WC2))[tid];

  // ---- per-ray setup ----
  float ox = rays_o[ray*3], oy = rays_o[ray*3+1], oz = rays_o[ray*3+2];
  float dx = rays_d[ray*3], dy = rays_d[ray*3+1], dz = rays_d[ray*3+2];
  float tnx = (-1.f-ox)/(dx+1e-15f), tfx = (1.f-ox)/(dx+1e-15f);
  float tny = (-1.f-oy)/(dy+1e-15f), tfy = (1.f-oy)/(dy+1e-15f);
  float tnz = (-1.f-oz)/(dz+1e-15f), tfz = (1.f-oz)/(dz+1e-15f);
  float nearv = fmaxf(fmaxf(fminf(tnx,tfx), fminf(tny,tfy)), fminf(tnz,tfz));
  float farv  = fminf(fminf(fmaxf(tnx,tfx), fmaxf(tny,tfy)), fmaxf(tnz,tfz));
  nearv = fmaxf(nearv, 0.05f);
  const float sd = (farv - nearv) * (1.f/64.f);

  // ---- coarse pass: wave 0 of each ray (lane = coarse sample) ----
  if (wir == 0){
    float zt = nearv + (farv-nearv) * ((float)lane * (1.f/63.f));
    float px = clampf(ox + dx*zt, -1.f, 1.f);
    float py = clampf(oy + dy*zt, -1.f, 1.f);
    float pz = clampf(oz + dz*zt, -1.f, 1.f);
    float acc = b20;
    #pragma unroll 8
    for (int j = 0; j < 64; ++j){
      float4 w = pW1[j];
      acc += fmaxf(px*w.x + py*w.y + pz*w.z + w.w, 0.f) * ws[OFF_W1E + 4*j + 3];
    }
    s_z[rs][lane] = zt;
    float s1  = __shfl_down(acc, 1);
    float zt1 = nearv + (farv-nearv) * ((float)(lane+1) * (1.f/63.f));
    float a_c = 0.f, qv = 1.f;
    if (lane < 63){
      float dc   = zt1 - zt;
      float mid  = 0.5f*(acc + s1);
      float cosv = clampf((s1-acc)/(dc+1e-5f), -1000.f, 0.f);
      float est  = cosv*dc*0.5f;
      float pcv  = sigm((mid-est)*64.f);
      float ncv  = sigm((mid+est)*64.f);
      a_c = clampf((pcv-ncv+1e-5f)/(pcv+1e-5f), 0.f, 1.f);
      qv  = 1.f - a_c + 1e-7f;
    }
    float p = qv;
    #pragma unroll
    for (int off = 1; off < 64; off <<= 1){
      float t = __shfl_up(p, off);
      if (lane >= off) p *= t;
    }
    float ec = __shfl_up(p, 1);
    if (lane == 0) ec = 1.f;
    float wvv = (lane < 63) ? (a_c*ec + 1e-5f) : 0.f;
    float tot = wvv;
    #pragma unroll
    for (int off = 32; off > 0; off >>= 1) tot += __shfl_xor(tot, off);
    float cs = wvv;
    #pragma unroll
    for (int off = 1; off < 64; off <<= 1){
      float t = __shfl_up(cs, off);
      if (lane >= off) cs += t;
    }
    if (lane == 0)  s_cdf[rs][0] = 0.f;
    if (lane < 63)  s_cdf[rs][lane+1] = cs / tot;
  }
  __syncthreads();

  // ---- sample_pdf (searchsorted right + lerp) ----
  if (wir == 0){
    float u = ((float)lane + 0.5f) * (1.f/64.f);
    int lo = 0, hi = 64;
    while (lo < hi){
      int m = (lo+hi) >> 1;
      if (s_cdf[rs][m] <= u) lo = m+1; else hi = m;
    }
    int below = lo - 1;
    int above = lo < 63 ? lo : 63;
    float cb = s_cdf[rs][below], ca = s_cdf[rs][above];
    float bb = s_z[rs][below],   ba = s_z[rs][above];
    float den = ca - cb; if (den < 1e-5f) den = 1.f;
    float tt = (u - cb)/den;
    s_newz[rs][lane] = bb + tt*(ba - bb);
  }
  __syncthreads();

  // A-fragments (weights, pre-swizzled bf16) — issue early to overlap latency
  const short8v* pAF = (const short8v*)(ws + OFF_AF);
  short8v af[10];
  #pragma unroll
  for (int f = 0; f < 10; ++f) af[f] = pAF[f*64 + lane];

  // ---- parallel merge of two sorted 64-lists ----
  {
    float v; int pos;
    if (lt < 64){
      v = s_z[rs][lt];
      int lo = 0, hi = 64;
      while (lo < hi){ int m=(lo+hi)>>1; if (s_newz[rs][m] < v) lo = m+1; else hi = m; }
      pos = lt + lo;
    } else {
      int jj = lt - 64;
      v = s_newz[rs][jj];
      int lo = 0, hi = 64;
      while (lo < hi){ int m=(lo+hi)>>1; if (s_z[rs][m] <= v) lo = m+1; else hi = m; }
      pos = jj + lo;
    }
    s_zall[rs][pos] = v;
  }
  __syncthreads();

  // ---- fine pass ----
  float zc = s_zall[rs][lt];
  float zn = s_zall[rs][lt < 127 ? lt+1 : 127];
  float delta = (lt < 127) ? (zn - zc) : sd;
  float zm    = (lt < 127) ? (zc + 0.5f*delta) : zc;
  float px = clampf(ox + dx*zm, -1.f, 1.f);
  float py = clampf(oy + dy*zm, -1.f, 1.f);
  float pz = clampf(oz + dz*zm, -1.f, 1.f);

  // layer-1 + sdf col-0 + FD grad via med3 identity:
  // relu(b+ew)-relu(b-ew) = sgn(w)*med3(b+e|w|, 0, 2e|w|)
  unsigned short* arow = &s_aext[wv][(unsigned)lane * KS];
  float sa = b20;
  float gxa = 0.f, gya = 0.f, gza = 0.f;
  #pragma unroll 2
  for (int j2 = 0; j2 < 32; ++j2){
    int j = 2*j2;
    float4 w0 = pW1[j],   e0 = pW1E[j],   s0 = pW1S[j];
    float4 w1 = pW1[j+1], e1 = pW1E[j+1], s1v = pW1S[j+1];
    float base0 = fmaf(px, w0.x, fmaf(py, w0.y, fmaf(pz, w0.z, w0.w)));
    float base1 = fmaf(px, w1.x, fmaf(py, w1.y, fmaf(pz, w1.z, w1.w)));
    float hv0 = fmaxf(base0, 0.f), hv1 = fmaxf(base1, 0.f);
    sa = fmaf(hv0, e0.w, sa); sa = fmaf(hv1, e1.w, sa);
    gxa = fmaf(__builtin_amdgcn_fmed3f(fmaf(0.5f, e0.x, base0), 0.f, e0.x), s0.x, gxa);
    gya = fmaf(__builtin_amdgcn_fmed3f(fmaf(0.5f, e0.y, base0), 0.f, e0.y), s0.y, gya);
    gza = fmaf(__builtin_amdgcn_fmed3f(fmaf(0.5f, e0.z, base0), 0.f, e0.z), s0.z, gza);
    gxa = fmaf(__builtin_amdgcn_fmed3f(fmaf(0.5f, e1.x, base1), 0.f, e1.x), s1v.x, gxa);
    gya = fmaf(__builtin_amdgcn_fmed3f(fmaf(0.5f, e1.y, base1), 0.f, e1.y), s1v.y, gya);
    gza = fmaf(__builtin_amdgcn_fmed3f(fmaf(0.5f, e1.z, base1), 0.f, e1.z), s1v.z, gza);
    *(unsigned*)&arow[j] = pk2(hv0, hv1);
  }
  float sdfv = sa;
  float gx = gxa*100.f, gy = gya*100.f, gz = gza*100.f;
  float gn = 1e-5f + sqrtf(gx*gx + gy*gy + gz*gz);
  float nx = gx/gn, ny = gy/gn, nz = gz/gn;

  // ext slots: k=64..72 = [pt,dir,n], k=73 = 1, k=74..79 = 0
  *(unsigned*)&arow[64] = pk2(px, py);
  *(unsigned*)&arow[66] = pk2(pz, dx);
  *(unsigned*)&arow[68] = pk2(dy, dz);
  *(unsigned*)&arow[70] = pk2(nx, ny);
  *(unsigned*)&arow[72] = pk2(nz, 1.0f);
  *(unsigned*)&arow[74] = 0u;
  *(unsigned*)&arow[76] = 0u;
  *(unsigned*)&arow[78] = 0u;

  // ---- NeuS alpha + transmittance scan (independent of MFMA -> hoisted) ----
  const float inv_s = expf(10.f * inv_s_p[0]);
  float tcos = dx*nx + dy*ny + dz*nz;
  float aarg = -100.f * tcos;
  float spv  = (aarg > 0.f) ? (aarg + log1pf(expf(-aarg))) : log1pf(expf(aarg));
  float iter_cos = -(spv * 0.01f);
  float est = iter_cos * delta * 0.5f;
  float pcv = sigm((sdfv - est)*inv_s);
  float ncv = sigm((sdfv + est)*inv_s);
  float alpha = clampf((pcv - ncv + 1e-5f)/(pcv + 1e-5f), 0.f, 1.f);

  float qv = 1.f - alpha + 1e-7f;
  float p = qv;
  #pragma unroll
  for (int off = 1; off < 64; off <<= 1){
    float t = __shfl_up(p, off);
    if (lane >= off) p *= t;
  }
  if (lane == 63) s_wtot[rs][wir] = p;
  __syncthreads();   // also fences aext LDS writes before MFMA reads
  float excl = __shfl_up(p, 1);
  if (lane == 0) excl = 1.f;
  if (wir == 1) excl *= s_wtot[rs][0];
  float w  = alpha * excl;

  // MFMA: C[c][s] = A(64x80) x aext^T(80x64), tiles (mb over c, nb over s)
  f32x16 acc00, acc01, acc10, acc11;
  #pragma unroll
  for (int i = 0; i < 16; ++i){ acc00[i]=0.f; acc01[i]=0.f; acc10[i]=0.f; acc11[i]=0.f; }
  const unsigned short* aw = s_aext[wv];
  const int scol = lane & 31;
  const int half8 = (lane >> 5) * 8;
  #pragma unroll
  for (int kk = 0; kk < 5; ++kk){
    int koff = 16*kk + half8;
    short8v b0 = lds_load8(&aw[ scol      * KS + koff]);
    short8v b1 = lds_load8(&aw[(32+scol) * KS + koff]);
    acc00 = __builtin_amdgcn_mfma_f32_32x32x16_bf16(af[kk],   b0, acc00, 0, 0, 0);
    acc10 = __builtin_amdgcn_mfma_f32_32x32x16_bf16(af[5+kk], b0, acc10, 0, 0, 0);
    acc01 = __builtin_amdgcn_mfma_f32_32x32x16_bf16(af[kk],   b1, acc01, 0, 0, 0);
    acc11 = __builtin_amdgcn_mfma_f32_32x32x16_bf16(af[5+kk], b1, acc11, 0, 0, 0);
  }

  // relu -> *Wc2 -> reduce over c: in-lane over regs, cross-half via shfl_xor(32)
  float pr0=0.f,pr1=0.f,pr2=0.f,pr3=0.f,pr4=0.f,pr5=0.f;
  const int halfoff = (lane >> 5) * 4;
  #pragma unroll
  for (int r = 0; r < 16; ++r){
    int ci = (r & 3) + 8*(r >> 2) + halfoff;
    float4 wA = s_wc2[ci];
    float4 wB = s_wc2[32 + ci];
    float v;
    v = fmaxf(acc00[r], 0.f); pr0 = fmaf(v, wA.x, pr0); pr1 = fmaf(v, wA.y, pr1); pr2 = fmaf(v, wA.z, pr2);
    v = fmaxf(acc10[r], 0.f); pr0 = fmaf(v, wB.x, pr0); pr1 = fmaf(v, wB.y, pr1); pr2 = fmaf(v, wB.z, pr2);
    v = fmaxf(acc01[r], 0.f); pr3 = fmaf(v, wA.x, pr3); pr4 = fmaf(v, wA.y, pr4); pr5 = fmaf(v, wA.z, pr5);
    v = fmaxf(acc11[r], 0.f); pr3 = fmaf(v, wB.x, pr3); pr4 = fmaf(v, wB.y, pr4); pr5 = fmaf(v, wB.z, pr5);
  }
  pr0 += __shfl_xor(pr0, 32); pr1 += __shfl_xor(pr1, 32); pr2 += __shfl_xor(pr2, 32);
  pr3 += __shfl_xor(pr3, 32); pr4 += __shfl_xor(pr4, 32); pr5 += __shfl_xor(pr5, 32);
  const bool hihalf = (lane >= 32);
  float c0 = sigm((hihalf ? pr3 : pr0) + pbc2[0]);
  float c1 = sigm((hihalf ? pr4 : pr1) + pbc2[1]);
  float c2 = sigm((hihalf ? pr5 : pr2) + pbc2[2]);

  // composite
  float r0 = w, r1 = w*c0, r2 = w*c1, r3 = w*c2;
  #pragma unroll
  for (int off = 32; off > 0; off >>= 1){
    r0 += __shfl_xor(r0, off);
    r1 += __shfl_xor(r1, off);
    r2 += __shfl_xor(r2, off);
    r3 += __shfl_xor(r3, off);
  }
  if (lane == 0){
    s_red[rs][wir][0]=r0; s_red[rs][wir][1]=r1; s_red[rs][wir][2]=r2; s_red[rs][wir][3]=r3;
  }
  __syncthreads();
  if (lt == 0){
    float wsum = s_red[rs][0][0] + s_red[rs][1][0];
    float bg = 1.f - wsum;
    out[ray*3+0] = s_red[rs][0][1] + s_red[rs][1][1] + bg;
    out[ray*3+1] = s_red[rs][0][2] + s_red[rs][1][2] + bg;
    out[ray*3+2] = s_red[rs][0][3] + s_red[rs][1][3] + bg;
  }
}

extern "C" void kernel_launch(void* const* d_in, const int* in_sizes, int n_in,
                              void* d_out, int out_size, void* d_ws, size_t ws_size,
                              hipStream_t stream)
{
  const float* rays_o = (const float*)d_in[0];
  const float* rays_d = (const float*)d_in[1];
  const float* W1  = (const float*)d_in[2];
  const float* b1  = (const float*)d_in[3];
  const float* W2  = (const float*)d_in[4];
  const float* b2  = (const float*)d_in[5];
  const float* Wc1 = (const float*)d_in[6];
  const float* bc1 = (const float*)d_in[7];
  const float* Wc2 = (const float*)d_in[8];
  const float* bc2 = (const float*)d_in[9];
  const float* inv_s = (const float*)d_in[10];
  float* out = (float*)d_out;
  float* ws  = (float*)d_ws;

  prep_weights<<<1, 256, 0, stream>>>(W1, b1, W2, b2, Wc1, bc1, Wc2, bc2, ws);

  const int R = in_sizes[0] / 3;               // 4096 rays
  dim3 grid(R / RAYS_PER_BLOCK), block(256);
  neus_render<<<grid, block, 0, stream>>>(rays_o, rays_d, inv_s, ws, out);
}